// Round 6
// baseline (24.452 us; speedup 1.0000x reference)
//
#include <hip/hip_runtime.h>

// FractalHilbertTokenizer: images (32,3,1024,1024) f32 -> tokens (32,4096,48) f32 ++ levels(4096)=6.
// Block = (b, level-3 Hilbert tile) = 8x8 leaves (128x128 px), 64 consecutive token ids.
// R6: cooperative FULL-LINE reads — lanes 0-31 load one contiguous 512B run (all lines of a
// tile row-segment are needed lines; only 16B of each 64B is kept, discarded in-register).
// Removes the 64-distinct-lines-per-wave-load divergence of R3. Writes unchanged (contiguous).

typedef float f4 __attribute__((ext_vector_type(4)));

#define B_ 32
#define MAIN_BLOCKS (B_ * 64)   // 2048 = exactly 8 blocks/CU * 256 CU

__global__ __launch_bounds__(256) void fht_gather6(const float* __restrict__ img,
                                                   float* __restrict__ out) {
    int bid = blockIdx.x;
    int tid = threadIdx.x;

    __shared__ f4 smem[768];               // 64 tokens x 48 floats = 12KB

    // levels tail folded into first 16 blocks (independent of the rest).
    if (bid < 16) {
        out[(size_t)B_ * 4096 * 48 + bid * 256 + tid] = 6.0f;
    }

    int t = bid & 63;                      // tile id (Hilbert levels 0..2)
    int b = bid >> 6;

    // Tile origin via forward ORDERS at l=0,1,2 (packs HW-validated in R0/R3).
    int Ty, Tx;
    {
        int d0 = (t >> 4) & 3, d1 = (t >> 2) & 3, d2 = t & 3;
        int q0 = (0xB4u >> (2 * d0)) & 3;
        int q1 = (0xD2u >> (2 * d1)) & 3;
        int q2 = (0x2Du >> (2 * d2)) & 3;
        Ty = ((q0 >> 1) << 2) | ((q1 >> 1) << 1) | (q2 >> 1);
        Tx = ((q0 & 1) << 2) | ((q1 & 1) << 1) | (q2 & 1);
    }
    int py = Ty << 7;
    int px = Tx << 7;

    // ---- cooperative full-line read: 3072 float4 = 48KB streamed, 12KB kept ----
    // idx -> c (plane), band (leaf row), row (0..3 within patch), j (float4 col in 512B run).
    // Lanes 0..31 of each half-wave cover one contiguous 512B run -> coalesced.
    const f4* ibase = reinterpret_cast<const f4*>(img);
#pragma unroll
    for (int k = 0; k < 12; ++k) {
        int idx  = (k << 8) + tid;         // 0..3071
        int c    = idx >> 10;              // 0..2
        int band = (idx >> 7) & 7;         // 0..7
        int row  = (idx >> 5) & 3;         // 0..3
        int j    = idx & 31;               // float4 col within tile row span

        f4 v = ibase[((size_t)(b * 3 + c) << 18) +
                     ((size_t)(py + band * 16 + row) << 8) +
                     (px >> 2) + j];

        if ((j & 3) == 0) {                // keep the leading 16B of each 64B leaf span
            int xl = j >> 2;               // 0..7 local leaf col
            // local Hilbert index, levels 3,4,5 -> inv packs 0x1E,0xB4,0xC9 (HW-validated).
            int q, d, nl = 0;
            q = (((band >> 2) & 1) << 1) | ((xl >> 2) & 1);
            d = (0x1Eu >> (2 * q)) & 3;  nl |= d << 4;
            q = (((band >> 1) & 1) << 1) | ((xl >> 1) & 1);
            d = (0xB4u >> (2 * q)) & 3;  nl |= d << 2;
            q = ((band & 1) << 1) | (xl & 1);
            d = (0xC9u >> (2 * q)) & 3;  nl |= d;
            smem[nl * 12 + c * 4 + row] = v;
        }
    }
    __syncthreads();

    // ---- contiguous 12,288B block write ----
    f4* dst = reinterpret_cast<f4*>(out) + (size_t)bid * 768;
#pragma unroll
    for (int k = 0; k < 3; ++k) {
        int w = tid + (k << 8);
        dst[w] = smem[w];
    }
}

extern "C" void kernel_launch(void* const* d_in, const int* in_sizes, int n_in,
                              void* d_out, int out_size, void* d_ws, size_t ws_size,
                              hipStream_t stream) {
    const float* img = (const float*)d_in[0];
    float* out = (float*)d_out;
    fht_gather6<<<MAIN_BLOCKS, 256, 0, stream>>>(img, out);
}

// Round 7
// 24.085 us; speedup vs baseline: 1.0152x; 1.0152x over previous
//
#include <hip/hip_runtime.h>

// FractalHilbertTokenizer: images (32,3,1024,1024) f32 -> tokens (32,4096,48) f32 ++ levels(4096)=6.
// Best-known structure (R3): block = (b, level-3 Hilbert tile) covering 8x8 leaves (128x128 px),
// whose 64 token indices are CONSECUTIVE. 16B reads (one per leaf row) -> LDS token layout ->
// contiguous 12KB block write. R7 = R3 + levels folded into the first 16 main blocks.
// Rejected by measurement: nt loads/stores (R5 -3%), full-line cooperative reads (R6 -3%),
// read-stream-major ordering (R2), write-stream-major ordering (R0).

#define B_ 32
#define MAIN_BLOCKS (B_ * 64)   // 2048

__global__ __launch_bounds__(256) void fht_gather7(const float* __restrict__ img,
                                                   float* __restrict__ out) {
    int bid = blockIdx.x;
    int tid = threadIdx.x;

    __shared__ float4 smem[768];           // 64 tokens x 48 floats = 12KB

    // levels tail folded in (first 16 blocks write 256 each).
    if (bid < 16) {
        out[(size_t)B_ * 4096 * 48 + bid * 256 + tid] = 6.0f;
    }

    int t = bid & 63;                      // tile id (Hilbert levels 0..2)
    int b = bid >> 6;

    // Tile origin via forward ORDERS at l=0,1,2 (packs HW-validated in R0/R3).
    int Ty, Tx;
    {
        int d0 = (t >> 4) & 3, d1 = (t >> 2) & 3, d2 = t & 3;
        int q0 = (0xB4u >> (2 * d0)) & 3;
        int q1 = (0xD2u >> (2 * d1)) & 3;
        int q2 = (0x2Du >> (2 * d2)) & 3;
        Ty = ((q0 >> 1) << 2) | ((q1 >> 1) << 1) | (q2 >> 1);
        Tx = ((q0 & 1) << 2) | ((q1 & 1) << 1) | (q2 & 1);
    }
    int py = Ty << 7;
    int px = Tx << 7;

    // ---- read + LDS scatter: 768 float4 items, 3 per thread (one per plane) ----
    int band = tid >> 5;                   // 0..7  local leaf row
    int i    = (tid >> 3) & 3;             // row within 4x4 patch
    int xl   = tid & 7;                    // 0..7  local leaf col

    const float4* base = reinterpret_cast<const float4*>(img) +
        ((size_t)(b * 3) << 18) +
        ((size_t)(py + band * 16 + i) << 8) +
        (px >> 2) + (xl << 2);

    float4 v0 = base[0];
    float4 v1 = base[1u << 18];
    float4 v2 = base[2u << 18];

    // Local Hilbert index from (band, xl): levels 3,4,5 -> inv packs 0x1E,0xB4,0xC9
    // (HW-validated in R2/R3).
    int nl = 0;
    {
        int q, d;
        q = (((band >> 2) & 1) << 1) | ((xl >> 2) & 1);
        d = (0x1Eu >> (2 * q)) & 3;  nl |= d << 4;
        q = (((band >> 1) & 1) << 1) | ((xl >> 1) & 1);
        d = (0xB4u >> (2 * q)) & 3;  nl |= d << 2;
        q = ((band & 1) << 1) | (xl & 1);
        d = (0xC9u >> (2 * q)) & 3;  nl |= d;
    }
    float4* sp = &smem[nl * 12 + i];
    sp[0] = v0;
    sp[4] = v1;
    sp[8] = v2;
    __syncthreads();

    // ---- contiguous 12,288B block write ----
    float4* dst = reinterpret_cast<float4*>(out) + (size_t)bid * 768;
#pragma unroll
    for (int k = 0; k < 3; ++k) {
        int w = tid + (k << 8);
        dst[w] = smem[w];
    }
}

extern "C" void kernel_launch(void* const* d_in, const int* in_sizes, int n_in,
                              void* d_out, int out_size, void* d_ws, size_t ws_size,
                              hipStream_t stream) {
    const float* img = (const float*)d_in[0];
    float* out = (float*)d_out;
    fht_gather7<<<MAIN_BLOCKS, 256, 0, stream>>>(img, out);
}